// Round 12
// baseline (289.081 us; speedup 1.0000x reference)
//
#include <hip/hip_runtime.h>

#define T_STEPS 60
#define HID 128
#define ROWS 16
#define NBLK (16384 / ROWS)  // 1024 blocks

typedef __attribute__((ext_vector_type(8))) short short8;
typedef __attribute__((ext_vector_type(4))) float f32x4;

#define K1 1.44269504088896340736f  // log2(e)

__device__ __forceinline__ unsigned short f2bf(float f) {
  unsigned u = __float_as_uint(f);
  return (unsigned short)((u + 0x7fffu + ((u >> 16) & 1u)) >> 16);
}
__device__ __forceinline__ float sigm(float x) {
  return __builtin_amdgcn_rcpf(1.0f + __expf(-x));
}
// butterfly-add over the 16-lane DPP row (sums l15 dimension, preserves l4)
template <int CTRL>
__device__ __forceinline__ float dppadd(float x) {
  int y = __builtin_amdgcn_update_dpp(0, __builtin_bit_cast(int, x), CTRL, 0xf,
                                      0xf, false);
  return x + __builtin_bit_cast(float, y);
}

// LDS map (bytes):
//   [0,4096):      h buffer 0 (16 rows x 128 units bf16, row r at r*256, swizzled)
//   [4096,8192):   h buffer 1
//   [8192,39168):  decode partials f32: [8 waves][60 t][16 rows], wave stride 968 f32
#define HB0 0
#define HB1 4096
#define PART 8192
#define WSTRIDE 968  // 60*16 + 8 pad (de-banks the 8 waves' b128 writes)
#define LDS_BYTES (PART + 8 * WSTRIDE * 4)

// (512,2): 128-reg/wave cap. (512,4) capped at 64 regs -> massive scratch
// spill (WRITE_SIZE 88 MB, R6-R11). State needs ~120 regs; must be (512,2).
__global__ __launch_bounds__(512, 2) void lstm_fused(
    const float* __restrict__ x, const float* __restrict__ W_enc,
    const float* __restrict__ b_enc, const float* __restrict__ W_ih,
    const float* __restrict__ W_hh, const float* __restrict__ b_ih,
    const float* __restrict__ b_hh, const float* __restrict__ W_dec,
    const float* __restrict__ b_dec, float* __restrict__ out) {
  __shared__ __align__(16) unsigned char lds[LDS_BYTES];

  const int tid = threadIdx.x;
  const int wav = tid >> 6;
  const int lane = tid & 63;
  const int l15 = lane & 15;
  const int l4 = lane >> 4;
  const int u = wav * 16 + l15;        // hidden unit owned by this lane
  const int row0 = blockIdx.x * ROWS;  // global batch row base

  // zero h buf0 (4096 B)
  for (int i = tid; i < 1024; i += 512) ((unsigned*)(lds + HB0))[i] = 0u;

  // ---- xp = enc @ W_ih^T + b_ih + b_hh, f32 IN REGISTERS, acc layout ----
  // (f16/LDS xp was the R3/R5 failure; must stay f32.)
  f32x4 xp4[4];
  {
    float xr0[4], xr1[4], xr2[4];
#pragma unroll
    for (int v = 0; v < 4; ++v) {
      int r = 4 * l4 + v;  // C-fragment row for this lane
      const float* xp_ = x + (size_t)(row0 + r) * 3;
      xr0[v] = xp_[0];
      xr1[v] = xp_[1];
      xr2[v] = xp_[2];
    }
#pragma unroll
    for (int gt = 0; gt < 4; ++gt) {
      float bias = b_ih[gt * 128 + u] + b_hh[gt * 128 + u];
#pragma unroll
      for (int v = 0; v < 4; ++v) xp4[gt][v] = bias;
    }
    const f32x4* wr0 = (const f32x4*)(W_ih + (size_t)u * 64);
    const f32x4* wr1 = (const f32x4*)(W_ih + (size_t)(128 + u) * 64);
    const f32x4* wr2 = (const f32x4*)(W_ih + (size_t)(256 + u) * 64);
    const f32x4* wr3 = (const f32x4*)(W_ih + (size_t)(384 + u) * 64);
    for (int e4 = 0; e4 < 16; ++e4) {
      f32x4 w0 = wr0[e4], w1 = wr1[e4], w2 = wr2[e4], w3 = wr3[e4];
#pragma unroll
      for (int j = 0; j < 4; ++j) {
        int e = e4 * 4 + j;
        float we0 = W_enc[e * 3], we1 = W_enc[e * 3 + 1], we2 = W_enc[e * 3 + 2];
        float be = b_enc[e];
#pragma unroll
        for (int v = 0; v < 4; ++v) {
          float ev = fmaf(we0, xr0[v], fmaf(we1, xr1[v], fmaf(we2, xr2[v], be)));
          xp4[0][v] = fmaf(w0[j], ev, xp4[0][v]);
          xp4[1][v] = fmaf(w1[j], ev, xp4[1][v]);
          xp4[2][v] = fmaf(w2[j], ev, xp4[2][v]);
          xp4[3][v] = fmaf(w3[j], ev, xp4[3][v]);
        }
      }
    }
    // prescale into exp2 domain: y = -log2e * preact (i,f,o), -2log2e (g)
#pragma unroll
    for (int gt = 0; gt < 4; ++gt) {
      float s = (gt == 2) ? (-2.0f * K1) : (-K1);
#pragma unroll
      for (int v = 0; v < 4; ++v) xp4[gt][v] *= s;
    }
  }

  // ---- W_hh bf16 B-fragments, prescaled into exp2 domain (R1-verified layout) ----
  short8 bw[4][4];
#pragma unroll
  for (int gt = 0; gt < 4; ++gt) {
    float s = (gt == 2) ? (-2.0f * K1) : (-K1);
#pragma unroll
    for (int kt = 0; kt < 4; ++kt) {
      const float* p = W_hh + (size_t)(gt * 128 + u) * HID + kt * 32 + 8 * l4;
      short8 f;
#pragma unroll
      for (int j = 0; j < 8; ++j) f[j] = (short)f2bf(s * p[j]);
      bw[gt][kt] = f;
    }
  }

  // c held in scaled domain: ct = -2log2e * c  (so e^{-2c} = 2^ct)
  float ct[4];
#pragma unroll
  for (int v = 0; v < 4; ++v) ct[v] = 0.0f;

  // ---- precomputed LDS addresses (swizzle bits 4-6, consistent on rd/wr) ----
  const unsigned swzA =
      (((unsigned)(l15 & 7)) << 4) ^ (((unsigned)(l15 & 8)) << 2);
  unsigned rdA[4];
#pragma unroll
  for (int kt = 0; kt < 4; ++kt)
    rdA[kt] = ((unsigned)(l15 * 256 + l4 * 16 + kt * 64)) ^ swzA;
  unsigned wrA[4];
#pragma unroll
  for (int v = 0; v < 4; ++v) {
    unsigned rr = (unsigned)(4 * l4 + v);
    wrA[v] = (rr * 256 + (unsigned)u * 2) ^ ((rr & 7u) << 4) ^ ((rr & 8u) << 2);
  }
  const float wdu = W_dec[u];  // decode weight for this lane's unit
  const unsigned ptByte = (unsigned)(wav * WSTRIDE + 4 * l4) * 4;
  const float kneg = -2.0f * K1;
  const float kpos = 2.0f * K1;

  __syncthreads();

  // gate math in exp2 domain (R7-verified):
  //   e^{-i}=2^acc0, e^{-f}=2^acc1, e^{-2g}=2^acc2, e^{-o}=2^acc3
  //   ct' = [ct*A*G + k(1-eg)*F]/(F*A*G), k=-2log2e;  h=(1-ec)/(Bo*(1+ec))
#define STEP(RB, WB, tcur)                                                     \
  {                                                                            \
    f32x4 acc[4];                                                              \
    {                                                                          \
      short8 af = *(const short8*)(lds + (RB) + rdA[0]);                       \
      _Pragma("unroll") for (int gt = 0; gt < 4; ++gt) acc[gt] =               \
          __builtin_amdgcn_mfma_f32_16x16x32_bf16(af, bw[gt][0], xp4[gt],      \
                                                  0, 0, 0);                    \
    }                                                                          \
    _Pragma("unroll") for (int kt = 1; kt < 4; ++kt) {                         \
      short8 af = *(const short8*)(lds + (RB) + rdA[kt]);                      \
      _Pragma("unroll") for (int gt = 0; gt < 4; ++gt) acc[gt] =               \
          __builtin_amdgcn_mfma_f32_16x16x32_bf16(af, bw[gt][kt], acc[gt],     \
                                                  0, 0, 0);                    \
    }                                                                          \
    f32x4 pz;                                                                  \
    _Pragma("unroll") for (int v = 0; v < 4; ++v) {                            \
      float ea = __builtin_amdgcn_exp2f(acc[0][v]);                            \
      float ef = __builtin_amdgcn_exp2f(acc[1][v]);                            \
      float eg = __builtin_amdgcn_exp2f(acc[2][v]);                            \
      float eo = __builtin_amdgcn_exp2f(acc[3][v]);                            \
      float A = 1.0f + ea, F = 1.0f + ef, G = 1.0f + eg, Bo = 1.0f + eo;       \
      float AG = A * G;                                                        \
      float r = __builtin_amdgcn_rcpf(F * AG);                                 \
      float tt = fmaf(kpos, eg, kneg);                                         \
      float num = fmaf(ct[v], AG, tt * F);                                     \
      float cn = num * r;                                                      \
      ct[v] = cn;                                                              \
      float ec = __builtin_amdgcn_exp2f(cn);                                   \
      float r2 = __builtin_amdgcn_rcpf(Bo * (1.0f + ec));                      \
      float h = (1.0f - ec) * r2;                                              \
      *(unsigned short*)(lds + (WB) + wrA[v]) = f2bf(h);                       \
      pz[v] = h * wdu;                                                         \
    }                                                                          \
    /* in-register 16-lane (l15) butterfly via DPP; l4 rows preserved */       \
    _Pragma("unroll") for (int v = 0; v < 4; ++v) pz[v] =                      \
        dppadd<0x140>(dppadd<0x141>(dppadd<0x4E>(dppadd<0xB1>(pz[v]))));       \
    if (l15 == 0)                                                              \
      *(f32x4*)(lds + PART + ptByte + (unsigned)(tcur)*64) = pz;               \
    __syncthreads();                                                           \
  }

  for (int t = 0; t < T_STEPS; t += 2) {
    STEP(HB0, HB1, t)
    STEP(HB1, HB0, t + 1)
  }
#undef STEP

  // ---- epilogue: cross-wave sum of partials + sigmoid + coalesced store ----
  const float bdec = b_dec[0];
  const float* partf = (const float*)(lds + PART);
  for (int i = tid; i < 16 * T_STEPS; i += 512) {
    int r = i / T_STEPS, t = i - r * T_STEPS;
    float s = 0.0f;
#pragma unroll
    for (int w = 0; w < 8; ++w) s += partf[w * WSTRIDE + t * 16 + r];
    out[(size_t)(row0 + r) * T_STEPS + t] = sigm(s + bdec);
  }
}

extern "C" void kernel_launch(void* const* d_in, const int* in_sizes, int n_in,
                              void* d_out, int out_size, void* d_ws, size_t ws_size,
                              hipStream_t stream) {
  const float* x = (const float*)d_in[0];
  const float* W_enc = (const float*)d_in[1];
  const float* b_enc = (const float*)d_in[2];
  const float* W_ih = (const float*)d_in[3];
  const float* W_hh = (const float*)d_in[4];
  const float* b_ih = (const float*)d_in[5];
  const float* b_hh = (const float*)d_in[6];
  const float* W_dec = (const float*)d_in[7];
  const float* b_dec = (const float*)d_in[8];
  float* out = (float*)d_out;

  dim3 grid(NBLK);  // 1024 blocks x 16 rows
  dim3 block(512);
  lstm_fused<<<grid, block, 0, stream>>>(x, W_enc, b_enc, W_ih, W_hh, b_ih, b_hh,
                                         W_dec, b_dec, out);
}

// Round 13
// 242.950 us; speedup vs baseline: 1.1899x; 1.1899x over previous
//
#include <hip/hip_runtime.h>

#define T_STEPS 60
#define HID 128
#define ROWS 16
#define NBLK (16384 / ROWS)  // 1024 blocks

typedef __attribute__((ext_vector_type(8))) short short8;
typedef __attribute__((ext_vector_type(4))) float f32x4;

#define K1 1.44269504088896340736f  // log2(e)

__device__ __forceinline__ unsigned short f2bf(float f) {
  unsigned u = __float_as_uint(f);
  return (unsigned short)((u + 0x7fffu + ((u >> 16) & 1u)) >> 16);
}
__device__ __forceinline__ float sigm(float x) {
  return __builtin_amdgcn_rcpf(1.0f + __expf(-x));
}
// butterfly-add over the 16-lane DPP row (sums l15 dimension, preserves l4)
template <int CTRL>
__device__ __forceinline__ float dppadd(float x) {
  int y = __builtin_amdgcn_update_dpp(0, __builtin_bit_cast(int, x), CTRL, 0xf,
                                      0xf, false);
  return x + __builtin_bit_cast(float, y);
}

// LDS map (bytes):
//   [0,4096):      h buffer 0 (16 rows x 128 units bf16, row r at r*256, swizzled)
//   [4096,8192):   h buffer 1
//   [8192,40960):  xp f32 in acc layout: gate gt at 8192+gt*8192+tid*16 (f32x4)
//                  (f32 = exact; the R3/R5 failure was f16 PRECISION, not LDS)
//   [40960,71936): decode partials f32: [8 waves][60 t][16 rows], stride 968 f32
#define HB0 0
#define HB1 4096
#define XP_BASE 8192
#define PART 40960
#define WSTRIDE 968  // 60*16 + 8 pad (de-banks the 8 waves' b128 writes)
#define LDS_BYTES (PART + 8 * WSTRIDE * 4)

// (512,4): 128-reg unified cap (VGPR+AGPR). In-loop demand with xp in LDS:
// bw 64 + acc 16 + ct 4 + addrs/consts/temps ~25 = ~110 < 128 -> no spill
// AND 4 waves/SIMD (2 blocks/CU). R11/R12 showed: spill-free at 1 block/CU
// (289us) loses to spilling at 2 blocks/CU (251us); this gets both.
__global__ __launch_bounds__(512, 4) void lstm_fused(
    const float* __restrict__ x, const float* __restrict__ W_enc,
    const float* __restrict__ b_enc, const float* __restrict__ W_ih,
    const float* __restrict__ W_hh, const float* __restrict__ b_ih,
    const float* __restrict__ b_hh, const float* __restrict__ W_dec,
    const float* __restrict__ b_dec, float* __restrict__ out) {
  __shared__ __align__(16) unsigned char lds[LDS_BYTES];

  const int tid = threadIdx.x;
  const int wav = tid >> 6;
  const int lane = tid & 63;
  const int l15 = lane & 15;
  const int l4 = lane >> 4;
  const int u = wav * 16 + l15;        // hidden unit owned by this lane
  const int row0 = blockIdx.x * ROWS;  // global batch row base

  // zero h buf0 (4096 B)
  for (int i = tid; i < 1024; i += 512) ((unsigned*)(lds + HB0))[i] = 0u;

  // ---- xp = enc @ W_ih^T + b_ih + b_hh -> LDS as f32 (exact), acc layout ----
  {
    f32x4 xp4[4];
    float xr0[4], xr1[4], xr2[4];
#pragma unroll
    for (int v = 0; v < 4; ++v) {
      int r = 4 * l4 + v;  // C-fragment row for this lane
      const float* xp_ = x + (size_t)(row0 + r) * 3;
      xr0[v] = xp_[0];
      xr1[v] = xp_[1];
      xr2[v] = xp_[2];
    }
#pragma unroll
    for (int gt = 0; gt < 4; ++gt) {
      float bias = b_ih[gt * 128 + u] + b_hh[gt * 128 + u];
#pragma unroll
      for (int v = 0; v < 4; ++v) xp4[gt][v] = bias;
    }
    const f32x4* wr0 = (const f32x4*)(W_ih + (size_t)u * 64);
    const f32x4* wr1 = (const f32x4*)(W_ih + (size_t)(128 + u) * 64);
    const f32x4* wr2 = (const f32x4*)(W_ih + (size_t)(256 + u) * 64);
    const f32x4* wr3 = (const f32x4*)(W_ih + (size_t)(384 + u) * 64);
    for (int e4 = 0; e4 < 16; ++e4) {
      f32x4 w0 = wr0[e4], w1 = wr1[e4], w2 = wr2[e4], w3 = wr3[e4];
#pragma unroll
      for (int j = 0; j < 4; ++j) {
        int e = e4 * 4 + j;
        float we0 = W_enc[e * 3], we1 = W_enc[e * 3 + 1], we2 = W_enc[e * 3 + 2];
        float be = b_enc[e];
#pragma unroll
        for (int v = 0; v < 4; ++v) {
          float ev = fmaf(we0, xr0[v], fmaf(we1, xr1[v], fmaf(we2, xr2[v], be)));
          xp4[0][v] = fmaf(w0[j], ev, xp4[0][v]);
          xp4[1][v] = fmaf(w1[j], ev, xp4[1][v]);
          xp4[2][v] = fmaf(w2[j], ev, xp4[2][v]);
          xp4[3][v] = fmaf(w3[j], ev, xp4[3][v]);
        }
      }
    }
    // prescale into exp2 domain: y = -log2e * preact (i,f,o), -2log2e (g)
    // then park in LDS (frees 16 regs for the loop)
#pragma unroll
    for (int gt = 0; gt < 4; ++gt) {
      float s = (gt == 2) ? (-2.0f * K1) : (-K1);
#pragma unroll
      for (int v = 0; v < 4; ++v) xp4[gt][v] *= s;
      *(f32x4*)(lds + XP_BASE + gt * 8192 + (unsigned)tid * 16) = xp4[gt];
    }
  }

  // ---- W_hh bf16 B-fragments, prescaled into exp2 domain (R1-verified layout) ----
  short8 bw[4][4];
#pragma unroll
  for (int gt = 0; gt < 4; ++gt) {
    float s = (gt == 2) ? (-2.0f * K1) : (-K1);
#pragma unroll
    for (int kt = 0; kt < 4; ++kt) {
      const float* p = W_hh + (size_t)(gt * 128 + u) * HID + kt * 32 + 8 * l4;
      short8 f;
#pragma unroll
      for (int j = 0; j < 8; ++j) f[j] = (short)f2bf(s * p[j]);
      bw[gt][kt] = f;
    }
  }

  // c held in scaled domain: ct = -2log2e * c  (so e^{-2c} = 2^ct)
  float ct[4];
#pragma unroll
  for (int v = 0; v < 4; ++v) ct[v] = 0.0f;

  // ---- precomputed LDS addresses (swizzle bits 4-6, consistent on rd/wr) ----
  const unsigned swzA =
      (((unsigned)(l15 & 7)) << 4) ^ (((unsigned)(l15 & 8)) << 2);
  unsigned rdA[4];
#pragma unroll
  for (int kt = 0; kt < 4; ++kt)
    rdA[kt] = ((unsigned)(l15 * 256 + l4 * 16 + kt * 64)) ^ swzA;
  unsigned wrA[4];
#pragma unroll
  for (int v = 0; v < 4; ++v) {
    unsigned rr = (unsigned)(4 * l4 + v);
    wrA[v] = (rr * 256 + (unsigned)u * 2) ^ ((rr & 7u) << 4) ^ ((rr & 8u) << 2);
  }
  const unsigned xpA = (unsigned)tid * 16;
  const float wdu = W_dec[u];  // decode weight for this lane's unit
  const unsigned ptByte = (unsigned)(wav * WSTRIDE + 4 * l4) * 4;
  const float kneg = -2.0f * K1;
  const float kpos = 2.0f * K1;

  __syncthreads();

  // gate math in exp2 domain (R7-verified):
  //   e^{-i}=2^acc0, e^{-f}=2^acc1, e^{-2g}=2^acc2, e^{-o}=2^acc3
  //   ct' = [ct*A*G + k(1-eg)*F]/(F*A*G), k=-2log2e;  h=(1-ec)/(Bo*(1+ec))
#define STEP(RB, WB, tcur)                                                     \
  {                                                                            \
    f32x4 xpr[4];                                                              \
    _Pragma("unroll") for (int gt = 0; gt < 4; ++gt) xpr[gt] =                 \
        *(const f32x4*)(lds + XP_BASE + gt * 8192 + xpA);                      \
    f32x4 acc[4];                                                              \
    {                                                                          \
      short8 af = *(const short8*)(lds + (RB) + rdA[0]);                       \
      _Pragma("unroll") for (int gt = 0; gt < 4; ++gt) acc[gt] =               \
          __builtin_amdgcn_mfma_f32_16x16x32_bf16(af, bw[gt][0], xpr[gt],      \
                                                  0, 0, 0);                    \
    }                                                                          \
    _Pragma("unroll") for (int kt = 1; kt < 4; ++kt) {                         \
      short8 af = *(const short8*)(lds + (RB) + rdA[kt]);                      \
      _Pragma("unroll") for (int gt = 0; gt < 4; ++gt) acc[gt] =               \
          __builtin_amdgcn_mfma_f32_16x16x32_bf16(af, bw[gt][kt], acc[gt],     \
                                                  0, 0, 0);                    \
    }                                                                          \
    f32x4 pz;                                                                  \
    _Pragma("unroll") for (int v = 0; v < 4; ++v) {                            \
      float ea = __builtin_amdgcn_exp2f(acc[0][v]);                            \
      float ef = __builtin_amdgcn_exp2f(acc[1][v]);                            \
      float eg = __builtin_amdgcn_exp2f(acc[2][v]);                            \
      float eo = __builtin_amdgcn_exp2f(acc[3][v]);                            \
      float A = 1.0f + ea, F = 1.0f + ef, G = 1.0f + eg, Bo = 1.0f + eo;       \
      float AG = A * G;                                                        \
      float r = __builtin_amdgcn_rcpf(F * AG);                                 \
      float tt = fmaf(kpos, eg, kneg);                                         \
      float num = fmaf(ct[v], AG, tt * F);                                     \
      float cn = num * r;                                                      \
      ct[v] = cn;                                                              \
      float ec = __builtin_amdgcn_exp2f(cn);                                   \
      float r2 = __builtin_amdgcn_rcpf(Bo * (1.0f + ec));                      \
      float h = (1.0f - ec) * r2;                                              \
      *(unsigned short*)(lds + (WB) + wrA[v]) = f2bf(h);                       \
      pz[v] = h * wdu;                                                         \
    }                                                                          \
    /* in-register 16-lane (l15) butterfly via DPP; l4 rows preserved */       \
    _Pragma("unroll") for (int v = 0; v < 4; ++v) pz[v] =                      \
        dppadd<0x140>(dppadd<0x141>(dppadd<0x4E>(dppadd<0xB1>(pz[v]))));       \
    if (l15 == 0)                                                              \
      *(f32x4*)(lds + PART + ptByte + (unsigned)(tcur)*64) = pz;               \
    __syncthreads();                                                           \
  }

  for (int t = 0; t < T_STEPS; t += 2) {
    STEP(HB0, HB1, t)
    STEP(HB1, HB0, t + 1)
  }
#undef STEP

  // ---- epilogue: cross-wave sum of partials + sigmoid + coalesced store ----
  const float bdec = b_dec[0];
  const float* partf = (const float*)(lds + PART);
  for (int i = tid; i < 16 * T_STEPS; i += 512) {
    int r = i / T_STEPS, t = i - r * T_STEPS;
    float s = 0.0f;
#pragma unroll
    for (int w = 0; w < 8; ++w) s += partf[w * WSTRIDE + t * 16 + r];
    out[(size_t)(row0 + r) * T_STEPS + t] = sigm(s + bdec);
  }
}

extern "C" void kernel_launch(void* const* d_in, const int* in_sizes, int n_in,
                              void* d_out, int out_size, void* d_ws, size_t ws_size,
                              hipStream_t stream) {
  const float* x = (const float*)d_in[0];
  const float* W_enc = (const float*)d_in[1];
  const float* b_enc = (const float*)d_in[2];
  const float* W_ih = (const float*)d_in[3];
  const float* W_hh = (const float*)d_in[4];
  const float* b_ih = (const float*)d_in[5];
  const float* b_hh = (const float*)d_in[6];
  const float* W_dec = (const float*)d_in[7];
  const float* b_dec = (const float*)d_in[8];
  float* out = (float*)d_out;

  dim3 grid(NBLK);  // 1024 blocks x 16 rows
  dim3 block(512);
  lstm_fused<<<grid, block, 0, stream>>>(x, W_enc, b_enc, W_ih, W_hh, b_ih, b_hh,
                                         W_dec, b_dec, out);
}

// Round 14
// 242.731 us; speedup vs baseline: 1.1909x; 1.0009x over previous
//
#include <hip/hip_runtime.h>

#define T_STEPS 60
#define HID 128
#define ROWS 16
#define NBLK (16384 / ROWS)  // 1024 blocks

typedef __attribute__((ext_vector_type(8))) short short8;
typedef __attribute__((ext_vector_type(4))) float f32x4;

#define K1 1.44269504088896340736f  // log2(e)

__device__ __forceinline__ unsigned short f2bf(float f) {
  unsigned u = __float_as_uint(f);
  return (unsigned short)((u + 0x7fffu + ((u >> 16) & 1u)) >> 16);
}
__device__ __forceinline__ float sigm(float x) {
  return __builtin_amdgcn_rcpf(1.0f + __expf(-x));
}
// butterfly-add over the 16-lane DPP row (sums l15 dimension, preserves l4)
template <int CTRL>
__device__ __forceinline__ float dppadd(float x) {
  int y = __builtin_amdgcn_update_dpp(0, __builtin_bit_cast(int, x), CTRL, 0xf,
                                      0xf, false);
  return x + __builtin_bit_cast(float, y);
}

// LDS map (bytes): identical to R13 (72KB static compiles & runs on gfx950)
//   [0,4096):      h buffer 0 (16 rows x 128 units bf16, row r at r*256, swizzled)
//   [4096,8192):   h buffer 1
//   [8192,40960):  xp f32 in acc layout: gate gt at 8192+gt*8192+tid*16 (f32x4)
//   [40960,71936): decode partials f32: [8 waves][60 t][16 rows], stride 968 f32
#define HB0 0
#define HB1 4096
#define XP_BASE 8192
#define PART 40960
#define WSTRIDE 968
#define LDS_BYTES (PART + 8 * WSTRIDE * 4)

// Unified reg budget at (512,4) = 128/wave. In-loop demand after diet:
// bw 64 (AGPR) + acc 16 + ct 4 + rd 2 + wr 4 + misc addrs/consts ~10 +
// af transients + ACT temps ~14 = ~114 < 128. Single-body loop (no unroll)
// prevents the 2-step pipelining that doubled transients in R13 (57MB spill).
__global__ __launch_bounds__(512, 4) void lstm_fused(
    const float* __restrict__ x, const float* __restrict__ W_enc,
    const float* __restrict__ b_enc, const float* __restrict__ W_ih,
    const float* __restrict__ W_hh, const float* __restrict__ b_ih,
    const float* __restrict__ b_hh, const float* __restrict__ W_dec,
    const float* __restrict__ b_dec, float* __restrict__ out) {
  __shared__ __align__(16) unsigned char lds[LDS_BYTES];

  const int tid = threadIdx.x;
  const int wav = tid >> 6;
  const int lane = tid & 63;
  const int l15 = lane & 15;
  const int l4 = lane >> 4;
  const int u = wav * 16 + l15;        // hidden unit owned by this lane
  const int row0 = blockIdx.x * ROWS;  // global batch row base

  // zero h buf0 (4096 B)
  for (int i = tid; i < 1024; i += 512) ((unsigned*)(lds + HB0))[i] = 0u;

  // ---- xp = enc @ W_ih^T + b_ih + b_hh -> LDS as f32 (exact), acc layout ----
  // (f16 xp was the R3/R5 failure: PRECISION, not location. f32 is exact.)
  {
    f32x4 xp4[4];
    float xr0[4], xr1[4], xr2[4];
#pragma unroll
    for (int v = 0; v < 4; ++v) {
      int r = 4 * l4 + v;
      const float* xp_ = x + (size_t)(row0 + r) * 3;
      xr0[v] = xp_[0];
      xr1[v] = xp_[1];
      xr2[v] = xp_[2];
    }
#pragma unroll
    for (int gt = 0; gt < 4; ++gt) {
      float bias = b_ih[gt * 128 + u] + b_hh[gt * 128 + u];
#pragma unroll
      for (int v = 0; v < 4; ++v) xp4[gt][v] = bias;
    }
    const f32x4* wr0 = (const f32x4*)(W_ih + (size_t)u * 64);
    const f32x4* wr1 = (const f32x4*)(W_ih + (size_t)(128 + u) * 64);
    const f32x4* wr2 = (const f32x4*)(W_ih + (size_t)(256 + u) * 64);
    const f32x4* wr3 = (const f32x4*)(W_ih + (size_t)(384 + u) * 64);
    for (int e4 = 0; e4 < 16; ++e4) {
      f32x4 w0 = wr0[e4], w1 = wr1[e4], w2 = wr2[e4], w3 = wr3[e4];
#pragma unroll
      for (int j = 0; j < 4; ++j) {
        int e = e4 * 4 + j;
        float we0 = W_enc[e * 3], we1 = W_enc[e * 3 + 1], we2 = W_enc[e * 3 + 2];
        float be = b_enc[e];
#pragma unroll
        for (int v = 0; v < 4; ++v) {
          float ev = fmaf(we0, xr0[v], fmaf(we1, xr1[v], fmaf(we2, xr2[v], be)));
          xp4[0][v] = fmaf(w0[j], ev, xp4[0][v]);
          xp4[1][v] = fmaf(w1[j], ev, xp4[1][v]);
          xp4[2][v] = fmaf(w2[j], ev, xp4[2][v]);
          xp4[3][v] = fmaf(w3[j], ev, xp4[3][v]);
        }
      }
    }
#pragma unroll
    for (int gt = 0; gt < 4; ++gt) {
      float s = (gt == 2) ? (-2.0f * K1) : (-K1);
#pragma unroll
      for (int v = 0; v < 4; ++v) xp4[gt][v] *= s;
      *(f32x4*)(lds + XP_BASE + gt * 8192 + (unsigned)tid * 16) = xp4[gt];
    }
  }

  // ---- W_hh bf16 B-fragments, prescaled into exp2 domain (R1-verified layout) ----
  short8 bw[4][4];
#pragma unroll
  for (int gt = 0; gt < 4; ++gt) {
    float s = (gt == 2) ? (-2.0f * K1) : (-K1);
#pragma unroll
    for (int kt = 0; kt < 4; ++kt) {
      const float* p = W_hh + (size_t)(gt * 128 + u) * HID + kt * 32 + 8 * l4;
      short8 f;
#pragma unroll
      for (int j = 0; j < 8; ++j) f[j] = (short)f2bf(s * p[j]);
      bw[gt][kt] = f;
    }
  }

  // c held in scaled domain: ct = -2log2e * c  (so e^{-2c} = 2^ct)
  float ct0 = 0.0f, ct1 = 0.0f, ct2 = 0.0f, ct3 = 0.0f;

  // ---- LDS addresses (swizzle bits 4-6; verified folds:
  //  kt=2,3 = rd0,rd1 + 128 (bit7, above swz, no carry); kt=1 NOT foldable) ----
  const unsigned swzA =
      (((unsigned)(l15 & 7)) << 4) ^ (((unsigned)(l15 & 8)) << 2);
  unsigned rd0 = ((unsigned)(l15 * 256 + l4 * 16)) ^ swzA;       // kt0, buf0
  unsigned rd1 = ((unsigned)(l15 * 256 + l4 * 16 + 64)) ^ swzA;  // kt1, buf0
  unsigned wr0, wr1, wr2, wr3;
  {
    unsigned rr = (unsigned)(4 * l4);
#define WRADDR(v) ((((rr + v) * 256 + (unsigned)u * 2) ^ (((rr + v) & 7u) << 4) ^ \
                    (((rr + v) & 8u) << 2)) + HB1)
    wr0 = WRADDR(0); wr1 = WRADDR(1); wr2 = WRADDR(2); wr3 = WRADDR(3);
#undef WRADDR
  }
  const unsigned xpA = (unsigned)tid * 16;
  const float wdu = W_dec[u];
  unsigned ptv = PART + (unsigned)(wav * WSTRIDE + 4 * l4) * 4;  // +=64/step
  const float kneg = -2.0f * K1;
  const float kpos = 2.0f * K1;

  __syncthreads();

  // gate math in exp2 domain (R7-verified):
  //   e^{-i}=2^acc0, e^{-f}=2^acc1, e^{-2g}=2^acc2, e^{-o}=2^acc3
  //   ct' = [ct*A*G + k(1-eg)*F]/(F*A*G), k=-2log2e;  h=(1-ec)/(Bo*(1+ec))
#pragma clang loop unroll(disable)
  for (int t = 0; t < T_STEPS; ++t) {
    f32x4 xpr0 = *(const f32x4*)(lds + XP_BASE + 0 * 8192 + xpA);
    f32x4 xpr1 = *(const f32x4*)(lds + XP_BASE + 1 * 8192 + xpA);
    f32x4 xpr2 = *(const f32x4*)(lds + XP_BASE + 2 * 8192 + xpA);
    f32x4 xpr3 = *(const f32x4*)(lds + XP_BASE + 3 * 8192 + xpA);
    short8 af0 = *(const short8*)(lds + rd0);
    short8 af1 = *(const short8*)(lds + rd1);
    short8 af2 = *(const short8*)(lds + rd0 + 128);
    short8 af3 = *(const short8*)(lds + rd1 + 128);
    f32x4 a0 = __builtin_amdgcn_mfma_f32_16x16x32_bf16(af0, bw[0][0], xpr0, 0, 0, 0);
    f32x4 a1 = __builtin_amdgcn_mfma_f32_16x16x32_bf16(af0, bw[1][0], xpr1, 0, 0, 0);
    f32x4 a2 = __builtin_amdgcn_mfma_f32_16x16x32_bf16(af0, bw[2][0], xpr2, 0, 0, 0);
    f32x4 a3 = __builtin_amdgcn_mfma_f32_16x16x32_bf16(af0, bw[3][0], xpr3, 0, 0, 0);
    a0 = __builtin_amdgcn_mfma_f32_16x16x32_bf16(af1, bw[0][1], a0, 0, 0, 0);
    a1 = __builtin_amdgcn_mfma_f32_16x16x32_bf16(af1, bw[1][1], a1, 0, 0, 0);
    a2 = __builtin_amdgcn_mfma_f32_16x16x32_bf16(af1, bw[2][1], a2, 0, 0, 0);
    a3 = __builtin_amdgcn_mfma_f32_16x16x32_bf16(af1, bw[3][1], a3, 0, 0, 0);
    a0 = __builtin_amdgcn_mfma_f32_16x16x32_bf16(af2, bw[0][2], a0, 0, 0, 0);
    a1 = __builtin_amdgcn_mfma_f32_16x16x32_bf16(af2, bw[1][2], a1, 0, 0, 0);
    a2 = __builtin_amdgcn_mfma_f32_16x16x32_bf16(af2, bw[2][2], a2, 0, 0, 0);
    a3 = __builtin_amdgcn_mfma_f32_16x16x32_bf16(af2, bw[3][2], a3, 0, 0, 0);
    a0 = __builtin_amdgcn_mfma_f32_16x16x32_bf16(af3, bw[0][3], a0, 0, 0, 0);
    a1 = __builtin_amdgcn_mfma_f32_16x16x32_bf16(af3, bw[1][3], a1, 0, 0, 0);
    a2 = __builtin_amdgcn_mfma_f32_16x16x32_bf16(af3, bw[2][3], a2, 0, 0, 0);
    a3 = __builtin_amdgcn_mfma_f32_16x16x32_bf16(af3, bw[3][3], a3, 0, 0, 0);

    float h[4];
    f32x4 pz;
#pragma unroll
    for (int v = 0; v < 4; ++v) {
      float ea = __builtin_amdgcn_exp2f(a0[v]);
      float ef = __builtin_amdgcn_exp2f(a1[v]);
      float eg = __builtin_amdgcn_exp2f(a2[v]);
      float eo = __builtin_amdgcn_exp2f(a3[v]);
      float A = 1.0f + ea, F = 1.0f + ef, G = 1.0f + eg, Bo = 1.0f + eo;
      float AG = A * G;
      float r = __builtin_amdgcn_rcpf(F * AG);
      float tt = fmaf(kpos, eg, kneg);
      float cprev = (v == 0) ? ct0 : (v == 1) ? ct1 : (v == 2) ? ct2 : ct3;
      float num = fmaf(cprev, AG, tt * F);
      float cn = num * r;
      if (v == 0) ct0 = cn; else if (v == 1) ct1 = cn; else if (v == 2) ct2 = cn; else ct3 = cn;
      float ec = __builtin_amdgcn_exp2f(cn);
      float r2 = __builtin_amdgcn_rcpf(Bo * (1.0f + ec));
      h[v] = (1.0f - ec) * r2;
      pz[v] = h[v] * wdu;
    }
    // pack h pairs with v_cvt_pk_bf16_f32 (RTNE, == f2bf rounding)
    unsigned r01, r23;
    asm("v_cvt_pk_bf16_f32 %0, %1, %2" : "=v"(r01) : "v"(h[0]), "v"(h[1]));
    asm("v_cvt_pk_bf16_f32 %0, %1, %2" : "=v"(r23) : "v"(h[2]), "v"(h[3]));
    *(unsigned short*)(lds + wr0) = (unsigned short)r01;
    *(unsigned short*)(lds + wr1) = (unsigned short)(r01 >> 16);
    *(unsigned short*)(lds + wr2) = (unsigned short)r23;
    *(unsigned short*)(lds + wr3) = (unsigned short)(r23 >> 16);
    // in-register 16-lane (l15) butterfly via DPP; l4 rows preserved
#pragma unroll
    for (int v = 0; v < 4; ++v)
      pz[v] = dppadd<0x140>(dppadd<0x141>(dppadd<0x4E>(dppadd<0xB1>(pz[v]))));
    if (l15 == 0) *(f32x4*)(lds + ptv) = pz;
    __syncthreads();
    rd0 ^= 4096; rd1 ^= 4096;
    wr0 ^= 4096; wr1 ^= 4096; wr2 ^= 4096; wr3 ^= 4096;
    ptv += 64;
  }

  // ---- epilogue: cross-wave sum of partials + sigmoid + coalesced store ----
  const float bdec = b_dec[0];
  const float* partf = (const float*)(lds + PART);
  for (int i = tid; i < 16 * T_STEPS; i += 512) {
    int r = i / T_STEPS, t = i - r * T_STEPS;
    float s = 0.0f;
#pragma unroll
    for (int w = 0; w < 8; ++w) s += partf[w * WSTRIDE + t * 16 + r];
    out[(size_t)(row0 + r) * T_STEPS + t] = sigm(s + bdec);
  }
}

extern "C" void kernel_launch(void* const* d_in, const int* in_sizes, int n_in,
                              void* d_out, int out_size, void* d_ws, size_t ws_size,
                              hipStream_t stream) {
  const float* x = (const float*)d_in[0];
  const float* W_enc = (const float*)d_in[1];
  const float* b_enc = (const float*)d_in[2];
  const float* W_ih = (const float*)d_in[3];
  const float* W_hh = (const float*)d_in[4];
  const float* b_ih = (const float*)d_in[5];
  const float* b_hh = (const float*)d_in[6];
  const float* W_dec = (const float*)d_in[7];
  const float* b_dec = (const float*)d_in[8];
  float* out = (float*)d_out;

  dim3 grid(NBLK);  // 1024 blocks x 16 rows
  dim3 block(512);
  lstm_fused<<<grid, block, 0, stream>>>(x, W_enc, b_enc, W_ih, W_hh, b_ih, b_hh,
                                         W_dec, b_dec, out);
}

// Round 15
// 239.412 us; speedup vs baseline: 1.2075x; 1.0139x over previous
//
#include <hip/hip_runtime.h>

#define T_STEPS 60
#define HID 128
#define ROWS 16
#define NBLK (16384 / ROWS)  // 1024 blocks

typedef __attribute__((ext_vector_type(8))) short short8;
typedef __attribute__((ext_vector_type(4))) float f32x4;

#define K1 1.44269504088896340736f  // log2(e)

__device__ __forceinline__ unsigned short f2bf(float f) {
  unsigned u = __float_as_uint(f);
  return (unsigned short)((u + 0x7fffu + ((u >> 16) & 1u)) >> 16);
}
__device__ __forceinline__ float sigm(float x) {
  return __builtin_amdgcn_rcpf(1.0f + __expf(-x));
}
// butterfly-add over the 16-lane DPP row (sums l15 dimension, preserves l4)
template <int CTRL>
__device__ __forceinline__ float dppadd(float x) {
  int y = __builtin_amdgcn_update_dpp(0, __builtin_bit_cast(int, x), CTRL, 0xf,
                                      0xf, false);
  return x + __builtin_bit_cast(float, y);
}

// LDS map (bytes): identical to R13/R14
//   [0,4096):      h buffer 0 (16 rows x 128 units bf16, row r at r*256, swizzled)
//   [4096,8192):   h buffer 1
//   [8192,40960):  xp f32 in acc layout: gate gt at 8192+gt*8192+tid*16 (f32x4)
//   [40960,71936): decode partials f32: [8 waves][60 t][16 rows], stride 968 f32
#define HB0 0
#define HB1 4096
#define XP_BASE 8192
#define PART 40960
#define WSTRIDE 968
#define LDS_BYTES (PART + 8 * WSTRIDE * 4)

// Spill diagnosis (R13/R14): arch-VGPR half of the 128 unified budget is 64
// (bw holds the other 64 as AGPRs). Loading all 4 af + 4 xpr up front peaks
// ~90 arch VGPRs -> per-step scratch (55 MB WRITE). Fix: two K-phases with
// sched_barrier(0) between; JIT xpr reads. Peak transients ~36.
__global__ __launch_bounds__(512, 4) void lstm_fused(
    const float* __restrict__ x, const float* __restrict__ W_enc,
    const float* __restrict__ b_enc, const float* __restrict__ W_ih,
    const float* __restrict__ W_hh, const float* __restrict__ b_ih,
    const float* __restrict__ b_hh, const float* __restrict__ W_dec,
    const float* __restrict__ b_dec, float* __restrict__ out) {
  __shared__ __align__(16) unsigned char lds[LDS_BYTES];

  const int tid = threadIdx.x;
  const int wav = tid >> 6;
  const int lane = tid & 63;
  const int l15 = lane & 15;
  const int l4 = lane >> 4;
  const int u = wav * 16 + l15;        // hidden unit owned by this lane
  const int row0 = blockIdx.x * ROWS;  // global batch row base

  // zero h buf0 (4096 B)
  for (int i = tid; i < 1024; i += 512) ((unsigned*)(lds + HB0))[i] = 0u;

  // ---- xp = enc @ W_ih^T + b_ih + b_hh -> LDS as f32 (exact), acc layout ----
  // (f16 xp was the R3/R5 failure: PRECISION, not location. f32 is exact.)
  {
    f32x4 xp4[4];
    float xr0[4], xr1[4], xr2[4];
#pragma unroll
    for (int v = 0; v < 4; ++v) {
      int r = 4 * l4 + v;
      const float* xp_ = x + (size_t)(row0 + r) * 3;
      xr0[v] = xp_[0];
      xr1[v] = xp_[1];
      xr2[v] = xp_[2];
    }
#pragma unroll
    for (int gt = 0; gt < 4; ++gt) {
      float bias = b_ih[gt * 128 + u] + b_hh[gt * 128 + u];
#pragma unroll
      for (int v = 0; v < 4; ++v) xp4[gt][v] = bias;
    }
    const f32x4* wr0 = (const f32x4*)(W_ih + (size_t)u * 64);
    const f32x4* wr1 = (const f32x4*)(W_ih + (size_t)(128 + u) * 64);
    const f32x4* wr2 = (const f32x4*)(W_ih + (size_t)(256 + u) * 64);
    const f32x4* wr3 = (const f32x4*)(W_ih + (size_t)(384 + u) * 64);
    for (int e4 = 0; e4 < 16; ++e4) {
      f32x4 w0 = wr0[e4], w1 = wr1[e4], w2 = wr2[e4], w3 = wr3[e4];
#pragma unroll
      for (int j = 0; j < 4; ++j) {
        int e = e4 * 4 + j;
        float we0 = W_enc[e * 3], we1 = W_enc[e * 3 + 1], we2 = W_enc[e * 3 + 2];
        float be = b_enc[e];
#pragma unroll
        for (int v = 0; v < 4; ++v) {
          float ev = fmaf(we0, xr0[v], fmaf(we1, xr1[v], fmaf(we2, xr2[v], be)));
          xp4[0][v] = fmaf(w0[j], ev, xp4[0][v]);
          xp4[1][v] = fmaf(w1[j], ev, xp4[1][v]);
          xp4[2][v] = fmaf(w2[j], ev, xp4[2][v]);
          xp4[3][v] = fmaf(w3[j], ev, xp4[3][v]);
        }
      }
    }
#pragma unroll
    for (int gt = 0; gt < 4; ++gt) {
      float s = (gt == 2) ? (-2.0f * K1) : (-K1);
#pragma unroll
      for (int v = 0; v < 4; ++v) xp4[gt][v] *= s;
      *(f32x4*)(lds + XP_BASE + gt * 8192 + (unsigned)tid * 16) = xp4[gt];
    }
  }

  // ---- W_hh bf16 B-fragments, prescaled into exp2 domain (R1-verified layout) ----
  short8 bw[4][4];
#pragma unroll
  for (int gt = 0; gt < 4; ++gt) {
    float s = (gt == 2) ? (-2.0f * K1) : (-K1);
#pragma unroll
    for (int kt = 0; kt < 4; ++kt) {
      const float* p = W_hh + (size_t)(gt * 128 + u) * HID + kt * 32 + 8 * l4;
      short8 f;
#pragma unroll
      for (int j = 0; j < 8; ++j) f[j] = (short)f2bf(s * p[j]);
      bw[gt][kt] = f;
    }
  }

  // c held in scaled domain: ct = -2log2e * c  (so e^{-2c} = 2^ct)
  float ct0 = 0.0f, ct1 = 0.0f, ct2 = 0.0f, ct3 = 0.0f;

  // ---- LDS addresses (swizzle bits 4-6; kt=2,3 fold as +128: bit7, no carry) ----
  const unsigned swzA =
      (((unsigned)(l15 & 7)) << 4) ^ (((unsigned)(l15 & 8)) << 2);
  unsigned rd0 = ((unsigned)(l15 * 256 + l4 * 16)) ^ swzA;       // kt0, buf0
  unsigned rd1 = ((unsigned)(l15 * 256 + l4 * 16 + 64)) ^ swzA;  // kt1, buf0
  unsigned wr0, wr1, wr2, wr3;
  {
    unsigned rr = (unsigned)(4 * l4);
#define WRADDR(v) ((((rr + v) * 256 + (unsigned)u * 2) ^ (((rr + v) & 7u) << 4) ^ \
                    (((rr + v) & 8u) << 2)) + HB1)
    wr0 = WRADDR(0); wr1 = WRADDR(1); wr2 = WRADDR(2); wr3 = WRADDR(3);
#undef WRADDR
  }
  const unsigned xpA = (unsigned)tid * 16;
  const float wdu = W_dec[u];
  unsigned ptv = PART + (unsigned)(wav * WSTRIDE + 4 * l4) * 4;  // +=64/step
  const float kneg = -2.0f * K1;
  const float kpos = 2.0f * K1;

  __syncthreads();

  // gate math in exp2 domain (R7-verified):
  //   e^{-i}=2^acc0, e^{-f}=2^acc1, e^{-2g}=2^acc2, e^{-o}=2^acc3
  //   ct' = [ct*A*G + k(1-eg)*F]/(F*A*G), k=-2log2e;  h=(1-ec)/(Bo*(1+ec))
#pragma clang loop unroll(disable)
  for (int t = 0; t < T_STEPS; ++t) {
    // ---- phase A: kt0,kt1 (af0,af1 live; xpr read JIT as MFMA C-init) ----
    short8 af0 = *(const short8*)(lds + rd0);
    short8 af1 = *(const short8*)(lds + rd1);
    f32x4 a0, a1, a2, a3;
    {
      f32x4 xpr = *(const f32x4*)(lds + XP_BASE + 0 * 8192 + xpA);
      a0 = __builtin_amdgcn_mfma_f32_16x16x32_bf16(af0, bw[0][0], xpr, 0, 0, 0);
    }
    {
      f32x4 xpr = *(const f32x4*)(lds + XP_BASE + 1 * 8192 + xpA);
      a1 = __builtin_amdgcn_mfma_f32_16x16x32_bf16(af0, bw[1][0], xpr, 0, 0, 0);
    }
    {
      f32x4 xpr = *(const f32x4*)(lds + XP_BASE + 2 * 8192 + xpA);
      a2 = __builtin_amdgcn_mfma_f32_16x16x32_bf16(af0, bw[2][0], xpr, 0, 0, 0);
    }
    {
      f32x4 xpr = *(const f32x4*)(lds + XP_BASE + 3 * 8192 + xpA);
      a3 = __builtin_amdgcn_mfma_f32_16x16x32_bf16(af0, bw[3][0], xpr, 0, 0, 0);
    }
    a0 = __builtin_amdgcn_mfma_f32_16x16x32_bf16(af1, bw[0][1], a0, 0, 0, 0);
    a1 = __builtin_amdgcn_mfma_f32_16x16x32_bf16(af1, bw[1][1], a1, 0, 0, 0);
    a2 = __builtin_amdgcn_mfma_f32_16x16x32_bf16(af1, bw[2][1], a2, 0, 0, 0);
    a3 = __builtin_amdgcn_mfma_f32_16x16x32_bf16(af1, bw[3][1], a3, 0, 0, 0);
    // pin: do NOT hoist phase-B loads above (caps arch-VGPR peak < 64)
    __builtin_amdgcn_sched_barrier(0);
    // ---- phase B: kt2,kt3 ----
    {
      short8 af2 = *(const short8*)(lds + rd0 + 128);
      short8 af3 = *(const short8*)(lds + rd1 + 128);
      a0 = __builtin_amdgcn_mfma_f32_16x16x32_bf16(af2, bw[0][2], a0, 0, 0, 0);
      a1 = __builtin_amdgcn_mfma_f32_16x16x32_bf16(af2, bw[1][2], a1, 0, 0, 0);
      a2 = __builtin_amdgcn_mfma_f32_16x16x32_bf16(af2, bw[2][2], a2, 0, 0, 0);
      a3 = __builtin_amdgcn_mfma_f32_16x16x32_bf16(af2, bw[3][2], a3, 0, 0, 0);
      a0 = __builtin_amdgcn_mfma_f32_16x16x32_bf16(af3, bw[0][3], a0, 0, 0, 0);
      a1 = __builtin_amdgcn_mfma_f32_16x16x32_bf16(af3, bw[1][3], a1, 0, 0, 0);
      a2 = __builtin_amdgcn_mfma_f32_16x16x32_bf16(af3, bw[2][3], a2, 0, 0, 0);
      a3 = __builtin_amdgcn_mfma_f32_16x16x32_bf16(af3, bw[3][3], a3, 0, 0, 0);
    }

    float h0, h1, h2, h3;
    f32x4 pz;
#pragma unroll
    for (int v = 0; v < 4; ++v) {
      float ea = __builtin_amdgcn_exp2f(a0[v]);
      float ef = __builtin_amdgcn_exp2f(a1[v]);
      float eg = __builtin_amdgcn_exp2f(a2[v]);
      float eo = __builtin_amdgcn_exp2f(a3[v]);
      float A = 1.0f + ea, F = 1.0f + ef, G = 1.0f + eg, Bo = 1.0f + eo;
      float AG = A * G;
      float r = __builtin_amdgcn_rcpf(F * AG);
      float tt = fmaf(kpos, eg, kneg);
      float cprev = (v == 0) ? ct0 : (v == 1) ? ct1 : (v == 2) ? ct2 : ct3;
      float num = fmaf(cprev, AG, tt * F);
      float cn = num * r;
      if (v == 0) ct0 = cn; else if (v == 1) ct1 = cn; else if (v == 2) ct2 = cn; else ct3 = cn;
      float ec = __builtin_amdgcn_exp2f(cn);
      float r2 = __builtin_amdgcn_rcpf(Bo * (1.0f + ec));
      float hh = (1.0f - ec) * r2;
      if (v == 0) h0 = hh; else if (v == 1) h1 = hh; else if (v == 2) h2 = hh; else h3 = hh;
      pz[v] = hh * wdu;
    }
    // pack h pairs with v_cvt_pk_bf16_f32 (RTNE, == f2bf rounding)
    unsigned r01, r23;
    asm("v_cvt_pk_bf16_f32 %0, %1, %2" : "=v"(r01) : "v"(h0), "v"(h1));
    asm("v_cvt_pk_bf16_f32 %0, %1, %2" : "=v"(r23) : "v"(h2), "v"(h3));
    *(unsigned short*)(lds + wr0) = (unsigned short)r01;
    *(unsigned short*)(lds + wr1) = (unsigned short)(r01 >> 16);
    *(unsigned short*)(lds + wr2) = (unsigned short)r23;
    *(unsigned short*)(lds + wr3) = (unsigned short)(r23 >> 16);
    // in-register 16-lane (l15) butterfly via DPP; l4 rows preserved
#pragma unroll
    for (int v = 0; v < 4; ++v)
      pz[v] = dppadd<0x140>(dppadd<0x141>(dppadd<0x4E>(dppadd<0xB1>(pz[v]))));
    if (l15 == 0) *(f32x4*)(lds + ptv) = pz;
    __syncthreads();
    rd0 ^= 4096; rd1 ^= 4096;
    wr0 ^= 4096; wr1 ^= 4096; wr2 ^= 4096; wr3 ^= 4096;
    ptv += 64;
  }

  // ---- epilogue: cross-wave sum of partials + sigmoid + coalesced store ----
  const float bdec = b_dec[0];
  const float* partf = (const float*)(lds + PART);
  for (int i = tid; i < 16 * T_STEPS; i += 512) {
    int r = i / T_STEPS, t = i - r * T_STEPS;
    float s = 0.0f;
#pragma unroll
    for (int w = 0; w < 8; ++w) s += partf[w * WSTRIDE + t * 16 + r];
    out[(size_t)(row0 + r) * T_STEPS + t] = sigm(s + bdec);
  }
}

extern "C" void kernel_launch(void* const* d_in, const int* in_sizes, int n_in,
                              void* d_out, int out_size, void* d_ws, size_t ws_size,
                              hipStream_t stream) {
  const float* x = (const float*)d_in[0];
  const float* W_enc = (const float*)d_in[1];
  const float* b_enc = (const float*)d_in[2];
  const float* W_ih = (const float*)d_in[3];
  const float* W_hh = (const float*)d_in[4];
  const float* b_ih = (const float*)d_in[5];
  const float* b_hh = (const float*)d_in[6];
  const float* W_dec = (const float*)d_in[7];
  const float* b_dec = (const float*)d_in[8];
  float* out = (float*)d_out;

  dim3 grid(NBLK);  // 1024 blocks x 16 rows
  dim3 block(512);
  lstm_fused<<<grid, block, 0, stream>>>(x, W_enc, b_enc, W_ih, W_hh, b_ih, b_hh,
                                         W_dec, b_dec, out);
}